// Round 4
// baseline (36.055 us; speedup 1.0000x reference)
//
#include <hip/hip_runtime.h>
#include <hip/hip_bf16.h>

#define ALPHA_C 0.3f
#define BETHE_C 1.2f
#define CH 4   // j-tiles per block chunk

typedef __attribute__((ext_vector_type(8))) short  frag_ab;   // 8 bf16 = 4 VGPR
typedef __attribute__((ext_vector_type(4))) float  frag_cd;   // 4 fp32 acc

// fp32 -> bf16 round-to-nearest-even
static __device__ __forceinline__ unsigned short f2bf(float f) {
    union { float f; unsigned int u; } cv;
    cv.f = f;
    unsigned int x = cv.u;
    unsigned int r = (x + 0x7fffu + ((x >> 16) & 1u)) >> 16;
    return (unsigned short)r;
}

static __device__ __forceinline__ void gl_lds16(const unsigned short* g, unsigned short* l) {
    __builtin_amdgcn_global_load_lds(
        (const __attribute__((address_space(1))) void*)g,
        (__attribute__((address_space(3))) void*)l,
        16, 0, 0);
}

__global__ void zero_kernel(float* out) { out[0] = 0.0f; }

// Pre-pass: fp32 X -> bf16, PRE-SWIZZLED (16B k-unit u stored at slot
// u ^ (row&7) within the 256B row; XOR touches only low 3 bits so each
// 128B half-row keeps its own units).
__global__ __launch_bounds__(256) void convert_kernel(
    const float* __restrict__ X, unsigned short* __restrict__ Xb, int nrows)
{
    const int tau = blockIdx.x * 256 + threadIdx.x;
    const int total = nrows * 16;
    if (tau >= total) return;
    const int row = tau >> 4;
    const int u   = tau & 15;
    const float* src = X + (size_t)row * 128 + u * 8;
    float4 a0 = *(const float4*)(src);
    float4 a1 = *(const float4*)(src + 4);
    frag_ab p;
    p[0] = (short)f2bf(a0.x); p[1] = (short)f2bf(a0.y);
    p[2] = (short)f2bf(a0.z); p[3] = (short)f2bf(a0.w);
    p[4] = (short)f2bf(a1.x); p[5] = (short)f2bf(a1.y);
    p[6] = (short)f2bf(a1.z); p[7] = (short)f2bf(a1.w);
    const int du = u ^ (row & 7);
    *(frag_ab*)((char*)Xb + (size_t)row * 256 + du * 16) = p;
}

// Stage one 16 KB B half-panel (128 rows x 64 k) into LDS, linear dest.
// Global source is per-lane (strided row gather of pre-swizzled halves).
static __device__ __forceinline__ void stageB(
    const unsigned short* __restrict__ Xb, unsigned short* buf,
    int jrow /* = j*128 */, int khalf, int wid, int lane)
{
    #pragma unroll
    for (int q = 0; q < 4; ++q) {
        const int c = wid * 256 + q * 64 + lane;          // 16B chunk id 0..1023
        const unsigned short* src =
            Xb + (size_t)(jrow + (c >> 3)) * 128 + khalf * 64 + (c & 7) * 8;
        gl_lds16(src, buf + (wid * 256 + q * 64) * 8);    // HW adds lane*16B
    }
}

// Persistent-chunk kernel: block = (row-panel i, chunk of up to CH j-tiles).
// A panel in registers; B double-buffered by K-half with counted vmcnt.
__global__ __launch_bounds__(256) void margin_persist(
    const unsigned short* __restrict__ Xb, const int* __restrict__ labels,
    float* __restrict__ partials, int NT)
{
    __shared__ unsigned short ldsA[128 * 128];        // 32 KB full-K A (swizzled)
    __shared__ unsigned short ldsB[2][128 * 64];      // 2 x 16 KB half-K B
    __shared__ int labA[128];
    __shared__ int labB[CH][128];
    __shared__ float wsum[4];

    const int i   = blockIdx.x;
    const int bid = blockIdx.y * gridDim.x + blockIdx.x;
    const int j0  = i + blockIdx.y * CH;
    const int t = threadIdx.x, lane = t & 63, wid = t >> 6;
    const int wr = wid >> 1, wc = wid & 1;

    if (j0 >= NT) { if (t == 0) partials[bid] = 0.f; return; }
    const int nj = min(CH, NT - j0);

    // ---- prologue: labels, A stage, first two B halves ----
    if (t < 128) labA[t] = labels[i * 128 + t];
    for (int jj = 0; jj < nj; ++jj)
        if (t < 128) labB[jj][t] = labels[(j0 + jj) * 128 + t];

    {   // A: 32 KB linear copy of pre-swizzled panel (8 gl_lds per wave)
        const unsigned short* gA = Xb + (size_t)i * 16384 + (wid * 512 + lane) * 8;
        unsigned short* lA = ldsA + wid * 4096;
        #pragma unroll
        for (int q = 0; q < 8; ++q)
            gl_lds16(gA + q * 512, lA + q * 512);
    }
    stageB(Xb, ldsB[0], j0 * 128, 0, wid, lane);          // S(0)
    stageB(Xb, ldsB[1], j0 * 128, 1, wid, lane);          // S(1)

    __syncthreads();   // full drain once: labels + A + S(0) + S(1) landed

    // ---- hoist A fragments into registers: avv[ks 0..3][m 0..3] ----
    const int g  = lane >> 4;
    const int rl = lane & 15;
    const int sw = rl & 7;

    frag_ab avv0[4], avv1[4], avv2[4], avv3[4];
    #pragma unroll
    for (int m = 0; m < 4; ++m) {
        const int row = wr * 64 + m * 16 + rl;
        const char* base = (const char*)ldsA + row * 256;
        avv0[m] = *(const frag_ab*)(base + (((0 * 4 + g) ^ sw) << 4));
        avv1[m] = *(const frag_ab*)(base + (((1 * 4 + g) ^ sw) << 4));
        avv2[m] = *(const frag_ab*)(base + (((2 * 4 + g) ^ sw) << 4));
        avv3[m] = *(const frag_ab*)(base + (((3 * 4 + g) ^ sw) << 4));
    }

    frag_cd acc[4][4];
    #pragma unroll
    for (int m = 0; m < 4; ++m)
        #pragma unroll
        for (int n = 0; n < 4; ++n)
            acc[m][n] = (frag_cd){0.f, 0.f, 0.f, 0.f};

    float lsum = 0.f;
    const int oc  = lane & 15;
    const int orr = (lane >> 4) * 4;

    // ---- main pipelined loop over j-tiles (2 K-halves each) ----
    for (int jj = 0; jj < nj; ++jj) {
        #pragma unroll
        for (int kh = 0; kh < 2; ++kh) {
            // wait for S(h) (own wave's loads), keep S(h+1) in flight
            if (kh == 0 || jj < nj - 1)
                asm volatile("s_waitcnt vmcnt(4)" ::: "memory");
            else
                asm volatile("s_waitcnt vmcnt(0)" ::: "memory");
            __builtin_amdgcn_s_barrier();      // all waves' S(h) visible

            const unsigned short* buf = ldsB[kh];
            #pragma unroll
            for (int ksl = 0; ksl < 2; ++ksl) {
                const int lu = ksl * 4 + g;    // local 16B k-unit 0..7
                frag_ab bv[4];
                #pragma unroll
                for (int n = 0; n < 4; ++n) {
                    const int row = wc * 64 + n * 16 + rl;
                    bv[n] = *(const frag_ab*)((const char*)buf +
                                row * 128 + ((lu ^ sw) << 4));
                }
                #pragma unroll
                for (int m = 0; m < 4; ++m) {
                    frag_ab a;
                    if (kh == 0) a = (ksl == 0) ? avv0[m] : avv1[m];
                    else         a = (ksl == 0) ? avv2[m] : avv3[m];
                    #pragma unroll
                    for (int n = 0; n < 4; ++n)
                        acc[m][n] = __builtin_amdgcn_mfma_f32_16x16x32_bf16(
                            a, bv[n], acc[m][n], 0, 0, 0);
                }
            }
            __builtin_amdgcn_s_barrier();      // all waves done reading buf[kh]
            if (jj < nj - 1)                   // S(h+2): next j, same half
                stageB(Xb, (unsigned short*)ldsB[kh],
                       (j0 + jj + 1) * 128, kh, wid, lane);
        }

        // ---- epilogue for tile j = j0+jj (overlaps in-flight loads) ----
        {
            float ts0 = 0.f, ts1 = 0.f;
            int lj[4];
            #pragma unroll
            for (int n = 0; n < 4; ++n) lj[n] = labB[jj][wc * 64 + n * 16 + oc];
            #pragma unroll
            for (int m = 0; m < 4; ++m) {
                #pragma unroll
                for (int r4 = 0; r4 < 4; ++r4) {
                    const int li = labA[wr * 64 + m * 16 + orr + r4];
                    #pragma unroll
                    for (int n = 0; n < 4; ++n) {
                        const float d  = acc[m][n][r4];
                        const bool eq  = (li == lj[n]);
                        const float c  = eq ? (ALPHA_C - BETHE_C) : (ALPHA_C + BETHE_C);
                        const float sd = eq ? d : -d;
                        if (n & 1) ts1 += fmaxf(sd + c, 0.f);
                        else       ts0 += fmaxf(sd + c, 0.f);
                    }
                    // reset acc for next tile
                    #pragma unroll
                    for (int n = 0; n < 4; ++n) acc[m][n][r4] = 0.f;
                }
            }
            const float w = (j0 + jj == i) ? 1.f : 2.f;
            lsum += w * (ts0 + ts1);
        }
    }

    // ---- block reduce -> partial ----
    #pragma unroll
    for (int off = 32; off > 0; off >>= 1)
        lsum += __shfl_down(lsum, off, 64);
    if (lane == 0) wsum[wid] = lsum;
    __syncthreads();
    if (t == 0) partials[bid] = wsum[0] + wsum[1] + wsum[2] + wsum[3];
}

// Final reduce: one block sums partials (fixed order -> deterministic).
__global__ __launch_bounds__(256) void reduce_kernel(
    const float* __restrict__ partials, float* __restrict__ out,
    int n, float inv_n)
{
    __shared__ float wsum[4];
    const int t    = threadIdx.x;
    const int lane = t & 63;
    const int wid  = t >> 6;
    float s = 0.f;
    for (int i = t; i < n; i += 256) s += partials[i];
    #pragma unroll
    for (int off = 32; off > 0; off >>= 1)
        s += __shfl_down(s, off, 64);
    if (lane == 0) wsum[wid] = s;
    __syncthreads();
    if (t == 0) out[0] = (wsum[0] + wsum[1] + wsum[2] + wsum[3]) * inv_n;
}

// ---------------- fallback (ws too small): round-1 fused kernel ----------------
__global__ __launch_bounds__(256) void margin_tile_kernel(
    const float* __restrict__ X, const int* __restrict__ labels,
    float* __restrict__ out, int NT, float inv_n)
{
    __shared__ unsigned short ldsA[128 * 64];
    __shared__ unsigned short ldsB[128 * 64];
    __shared__ int labA[128];
    __shared__ int labB[128];
    __shared__ float wsum[4];

    int b = blockIdx.x;
    int ti = 0;
    while (b >= NT - ti) { b -= NT - ti; ++ti; }
    const int tj = ti + b;

    const int t    = threadIdx.x;
    const int lane = t & 63;
    const int wid  = t >> 6;
    const int wr   = wid >> 1;
    const int wc   = wid & 1;

    const int rowA = ti * 128;
    const int rowB = tj * 128;

    if (t < 128) labA[t] = labels[rowA + t];
    else         labB[t - 128] = labels[rowB + (t - 128)];

    frag_cd acc[4][4];
    #pragma unroll
    for (int m = 0; m < 4; ++m)
        #pragma unroll
        for (int n = 0; n < 4; ++n)
            acc[m][n] = (frag_cd){0.f, 0.f, 0.f, 0.f};

    const int g  = lane >> 4;
    const int rl = lane & 15;

    for (int kh = 0; kh < 2; ++kh) {
        __syncthreads();
        #pragma unroll
        for (int it = 0; it < 4; ++it) {
            const int c  = it * 256 + t;
            const int r  = c >> 3;
            const int c8 = c & 7;
            const float* srcA = X + (size_t)(rowA + r) * 128 + kh * 64 + c8 * 8;
            const float* srcB = X + (size_t)(rowB + r) * 128 + kh * 64 + c8 * 8;
            float4 a0 = *(const float4*)(srcA);
            float4 a1 = *(const float4*)(srcA + 4);
            float4 b0 = *(const float4*)(srcB);
            float4 b1 = *(const float4*)(srcB + 4);
            const int byte = r * 128 + (((c8 << 4)) ^ ((r & 7) << 4));
            frag_ab pa, pb;
            pa[0] = (short)f2bf(a0.x); pa[1] = (short)f2bf(a0.y);
            pa[2] = (short)f2bf(a0.z); pa[3] = (short)f2bf(a0.w);
            pa[4] = (short)f2bf(a1.x); pa[5] = (short)f2bf(a1.y);
            pa[6] = (short)f2bf(a1.z); pa[7] = (short)f2bf(a1.w);
            pb[0] = (short)f2bf(b0.x); pb[1] = (short)f2bf(b0.y);
            pb[2] = (short)f2bf(b0.z); pb[3] = (short)f2bf(b0.w);
            pb[4] = (short)f2bf(b1.x); pb[5] = (short)f2bf(b1.y);
            pb[6] = (short)f2bf(b1.z); pb[7] = (short)f2bf(b1.w);
            *(frag_ab*)((char*)ldsA + byte) = pa;
            *(frag_ab*)((char*)ldsB + byte) = pb;
        }
        __syncthreads();
        #pragma unroll
        for (int ks = 0; ks < 2; ++ks) {
            const int kbyte = ks * 64 + g * 16;
            frag_ab av[4], bv[4];
            #pragma unroll
            for (int m = 0; m < 4; ++m) {
                const int row = wr * 64 + m * 16 + rl;
                av[m] = *(const frag_ab*)((const char*)ldsA +
                            row * 128 + (kbyte ^ ((row & 7) << 4)));
            }
            #pragma unroll
            for (int n = 0; n < 4; ++n) {
                const int row = wc * 64 + n * 16 + rl;
                bv[n] = *(const frag_ab*)((const char*)ldsB +
                            row * 128 + (kbyte ^ ((row & 7) << 4)));
            }
            #pragma unroll
            for (int m = 0; m < 4; ++m)
                #pragma unroll
                for (int n = 0; n < 4; ++n)
                    acc[m][n] = __builtin_amdgcn_mfma_f32_16x16x32_bf16(
                        av[m], bv[n], acc[m][n], 0, 0, 0);
        }
    }

    float lsum = 0.f;
    const int oc  = lane & 15;
    const int orr = (lane >> 4) * 4;

    int lj[4];
    #pragma unroll
    for (int n = 0; n < 4; ++n) lj[n] = labB[wc * 64 + n * 16 + oc];

    #pragma unroll
    for (int m = 0; m < 4; ++m) {
        #pragma unroll
        for (int j = 0; j < 4; ++j) {
            const int li = labA[wr * 64 + m * 16 + orr + j];
            #pragma unroll
            for (int n = 0; n < 4; ++n) {
                const float d = acc[m][n][j];
                const float s = (li == lj[n]) ? 1.f : -1.f;
                lsum += fmaxf(fmaf(s, d - BETHE_C, ALPHA_C), 0.f);
            }
        }
    }

    const float w = (ti == tj) ? 1.f : 2.f;
    lsum *= w * inv_n;

    #pragma unroll
    for (int off = 32; off > 0; off >>= 1)
        lsum += __shfl_down(lsum, off, 64);

    if (lane == 0) wsum[wid] = lsum;
    __syncthreads();
    if (t == 0) atomicAdd(out, wsum[0] + wsum[1] + wsum[2] + wsum[3]);
}

extern "C" void kernel_launch(void* const* d_in, const int* in_sizes, int n_in,
                              void* d_out, int out_size, void* d_ws, size_t ws_size,
                              hipStream_t stream) {
    const float* X      = (const float*)d_in[0];
    const int*   labels = (const int*)d_in[1];
    float*       out    = (float*)d_out;

    const int N   = in_sizes[1];             // 8192
    const int NT  = N / 128;                 // 64
    const int NCH = (NT + CH - 1) / CH;      // 16
    const int npart = NT * NCH;              // 1024

    const size_t xb_bytes = (size_t)N * 128 * sizeof(unsigned short);  // 2 MB
    const size_t need     = xb_bytes + (size_t)npart * sizeof(float);

    if (ws_size >= need) {
        unsigned short* Xb       = (unsigned short*)d_ws;
        float*          partials = (float*)((char*)d_ws + xb_bytes);
        const int cblocks = (N * 16 + 255) / 256;
        convert_kernel<<<cblocks, 256, 0, stream>>>(X, Xb, N);
        margin_persist<<<dim3(NT, NCH), 256, 0, stream>>>(Xb, labels, partials, NT);
        reduce_kernel<<<1, 256, 0, stream>>>(partials, out, npart, 1.0f / (float)N);
    } else {
        const int nblocks = NT * (NT + 1) / 2;
        zero_kernel<<<1, 1, 0, stream>>>(out);
        margin_tile_kernel<<<nblocks, 256, 0, stream>>>(X, labels, out, NT, 1.0f / (float)N);
    }
}

// Round 5
// 34.874 us; speedup vs baseline: 1.0339x; 1.0339x over previous
//
#include <hip/hip_runtime.h>
#include <hip/hip_bf16.h>

#define ALPHA_C 0.3f
#define BETHE_C 1.2f
#define CH 4   // j-panels (64 rows each) per block

typedef __attribute__((ext_vector_type(8))) short  frag_ab;   // 8 bf16 = 4 VGPR
typedef __attribute__((ext_vector_type(4))) float  frag_cd;   // 4 fp32 acc

// fp32 -> bf16 round-to-nearest-even
static __device__ __forceinline__ unsigned short f2bf(float f) {
    union { float f; unsigned int u; } cv;
    cv.f = f;
    unsigned int x = cv.u;
    unsigned int r = (x + 0x7fffu + ((x >> 16) & 1u)) >> 16;
    return (unsigned short)r;
}

__global__ void zero_kernel(float* out) { out[0] = 0.0f; }

// Pre-pass: X fp32 [N][128] -> Xb bf16 in FRAGMENT-LINEAR layout.
// Tile T = R*4 + ks  (R = row/16, ks = k/32); within tile, lane l holds
// row R*16+(l&15), k = ks*32+(l>>4)*8 .. +8  => 16 B at byte T*1024 + l*16.
// Writes are perfectly coalesced (64 threads <-> one 1 KB tile).
__global__ __launch_bounds__(256) void convert_kernel(
    const float* __restrict__ X, unsigned short* __restrict__ Xb, int nrows)
{
    const int tau = blockIdx.x * 256 + threadIdx.x;
    const int total = nrows * 16;             // (nrows/16 tiles-rows)*4 ks*64 lanes
    if (tau >= total) return;
    const int T = tau >> 6;
    const int l = tau & 63;
    const int R  = T >> 2;
    const int ks = T & 3;
    const int row = R * 16 + (l & 15);
    const int k   = ks * 32 + (l >> 4) * 8;
    const float* src = X + (size_t)row * 128 + k;
    float4 a0 = *(const float4*)(src);
    float4 a1 = *(const float4*)(src + 4);
    frag_ab p;
    p[0] = (short)f2bf(a0.x); p[1] = (short)f2bf(a0.y);
    p[2] = (short)f2bf(a0.z); p[3] = (short)f2bf(a0.w);
    p[4] = (short)f2bf(a1.x); p[5] = (short)f2bf(a1.y);
    p[6] = (short)f2bf(a1.z); p[7] = (short)f2bf(a1.w);
    *(frag_ab*)((char*)Xb + (size_t)T * 1024 + l * 16) = p;
}

// Main: 1 wave per block (64 threads), ZERO LDS, ZERO barriers.
// Block (i, c) computes 64x64 output tiles (i, j) for j = i+c*CH .. +CH.
// A fragments register-resident (16 frags); B fragments loaded per ks
// directly global->reg (coalesced 1 KB loads from L2-resident Xb).
__global__ __launch_bounds__(64, 2) void margin_reg(
    const unsigned short* __restrict__ Xb, const int* __restrict__ labels,
    float* __restrict__ partials, int NP)
{
    const int i   = blockIdx.x;                       // row panel (64 rows)
    const int bid = blockIdx.y * gridDim.x + blockIdx.x;
    const int j0  = i + blockIdx.y * CH;
    const int l   = threadIdx.x;                      // 0..63

    if (j0 >= NP) { if (l == 0) partials[bid] = 0.f; return; }
    const int nj = min(CH, NP - j0);

    // ---- A fragments: row-tiles i*4+m, all 4 k-steps -> 64 VGPRs ----
    frag_ab avv[4][4];   // [ks][m]
    #pragma unroll
    for (int m = 0; m < 4; ++m)
        #pragma unroll
        for (int ks = 0; ks < 4; ++ks)
            avv[ks][m] = *(const frag_ab*)(Xb +
                (size_t)((i * 4 + m) * 4 + ks) * 512 + l * 8);

    // ---- per-lane A labels: row = i*64 + m*16 + (l>>4)*4 + r4 ----
    int labi[4][4];
    #pragma unroll
    for (int m = 0; m < 4; ++m)
        #pragma unroll
        for (int r4 = 0; r4 < 4; ++r4)
            labi[m][r4] = labels[i * 64 + m * 16 + ((l >> 4) << 2) + r4];

    float lsum = 0.f;

    for (int jj = 0; jj < nj; ++jj) {
        const int j = j0 + jj;

        frag_cd acc[4][4];
        #pragma unroll
        for (int m = 0; m < 4; ++m)
            #pragma unroll
            for (int n = 0; n < 4; ++n)
                acc[m][n] = (frag_cd){0.f, 0.f, 0.f, 0.f};

        #pragma unroll
        for (int ks = 0; ks < 4; ++ks) {
            frag_ab bv[4];
            #pragma unroll
            for (int n = 0; n < 4; ++n)
                bv[n] = *(const frag_ab*)(Xb +
                    (size_t)((j * 4 + n) * 4 + ks) * 512 + l * 8);
            #pragma unroll
            for (int m = 0; m < 4; ++m)
                #pragma unroll
                for (int n = 0; n < 4; ++n)
                    acc[m][n] = __builtin_amdgcn_mfma_f32_16x16x32_bf16(
                        avv[ks][m], bv[n], acc[m][n], 0, 0, 0);
        }

        int labj[4];
        #pragma unroll
        for (int n = 0; n < 4; ++n)
            labj[n] = labels[j * 64 + n * 16 + (l & 15)];

        // hinge epilogue: eq ? max(0, d+(a-b)) : max(0, (a+b)-d)
        float ts = 0.f;
        #pragma unroll
        for (int m = 0; m < 4; ++m) {
            #pragma unroll
            for (int r4 = 0; r4 < 4; ++r4) {
                const int li = labi[m][r4];
                #pragma unroll
                for (int n = 0; n < 4; ++n) {
                    const float d = acc[m][n][r4];
                    const float v = (li == labj[n])
                        ? (d + (ALPHA_C - BETHE_C))
                        : ((ALPHA_C + BETHE_C) - d);
                    ts += fmaxf(v, 0.f);
                }
            }
        }
        lsum += (j == i) ? ts : 2.f * ts;
    }

    // wave-level reduce, no LDS
    #pragma unroll
    for (int off = 32; off > 0; off >>= 1)
        lsum += __shfl_down(lsum, off, 64);
    if (l == 0) partials[bid] = lsum;
}

// Final reduce: one block sums partials (fixed order -> deterministic).
__global__ __launch_bounds__(256) void reduce_kernel(
    const float* __restrict__ partials, float* __restrict__ out,
    int n, float inv_n)
{
    __shared__ float wsum[4];
    const int t    = threadIdx.x;
    const int lane = t & 63;
    const int wid  = t >> 6;
    float s = 0.f;
    for (int idx = t; idx < n; idx += 256) s += partials[idx];
    #pragma unroll
    for (int off = 32; off > 0; off >>= 1)
        s += __shfl_down(s, off, 64);
    if (lane == 0) wsum[wid] = s;
    __syncthreads();
    if (t == 0) out[0] = (wsum[0] + wsum[1] + wsum[2] + wsum[3]) * inv_n;
}

// ---------------- fallback (ws too small / odd N): round-1 fused kernel ----------------
__global__ __launch_bounds__(256) void margin_tile_kernel(
    const float* __restrict__ X, const int* __restrict__ labels,
    float* __restrict__ out, int NT, float inv_n)
{
    __shared__ unsigned short ldsA[128 * 64];
    __shared__ unsigned short ldsB[128 * 64];
    __shared__ int labA[128];
    __shared__ int labB[128];
    __shared__ float wsum[4];

    int b = blockIdx.x;
    int ti = 0;
    while (b >= NT - ti) { b -= NT - ti; ++ti; }
    const int tj = ti + b;

    const int t    = threadIdx.x;
    const int lane = t & 63;
    const int wid  = t >> 6;
    const int wr   = wid >> 1;
    const int wc   = wid & 1;

    const int rowA = ti * 128;
    const int rowB = tj * 128;

    if (t < 128) labA[t] = labels[rowA + t];
    else         labB[t - 128] = labels[rowB + (t - 128)];

    frag_cd acc[4][4];
    #pragma unroll
    for (int m = 0; m < 4; ++m)
        #pragma unroll
        for (int n = 0; n < 4; ++n)
            acc[m][n] = (frag_cd){0.f, 0.f, 0.f, 0.f};

    const int g  = lane >> 4;
    const int rl = lane & 15;

    for (int kh = 0; kh < 2; ++kh) {
        __syncthreads();
        #pragma unroll
        for (int it = 0; it < 4; ++it) {
            const int c  = it * 256 + t;
            const int r  = c >> 3;
            const int c8 = c & 7;
            const float* srcA = X + (size_t)(rowA + r) * 128 + kh * 64 + c8 * 8;
            const float* srcB = X + (size_t)(rowB + r) * 128 + kh * 64 + c8 * 8;
            float4 a0 = *(const float4*)(srcA);
            float4 a1 = *(const float4*)(srcA + 4);
            float4 b0 = *(const float4*)(srcB);
            float4 b1 = *(const float4*)(srcB + 4);
            const int byte = r * 128 + (((c8 << 4)) ^ ((r & 7) << 4));
            frag_ab pa, pb;
            pa[0] = (short)f2bf(a0.x); pa[1] = (short)f2bf(a0.y);
            pa[2] = (short)f2bf(a0.z); pa[3] = (short)f2bf(a0.w);
            pa[4] = (short)f2bf(a1.x); pa[5] = (short)f2bf(a1.y);
            pa[6] = (short)f2bf(a1.z); pa[7] = (short)f2bf(a1.w);
            pb[0] = (short)f2bf(b0.x); pb[1] = (short)f2bf(b0.y);
            pb[2] = (short)f2bf(b0.z); pb[3] = (short)f2bf(b0.w);
            pb[4] = (short)f2bf(b1.x); pb[5] = (short)f2bf(b1.y);
            pb[6] = (short)f2bf(b1.z); pb[7] = (short)f2bf(b1.w);
            *(frag_ab*)((char*)ldsA + byte) = pa;
            *(frag_ab*)((char*)ldsB + byte) = pb;
        }
        __syncthreads();
        #pragma unroll
        for (int ks = 0; ks < 2; ++ks) {
            const int kbyte = ks * 64 + g * 16;
            frag_ab av[4], bv[4];
            #pragma unroll
            for (int m = 0; m < 4; ++m) {
                const int row = wr * 64 + m * 16 + rl;
                av[m] = *(const frag_ab*)((const char*)ldsA +
                            row * 128 + (kbyte ^ ((row & 7) << 4)));
            }
            #pragma unroll
            for (int n = 0; n < 4; ++n) {
                const int row = wc * 64 + n * 16 + rl;
                bv[n] = *(const frag_ab*)((const char*)ldsB +
                            row * 128 + (kbyte ^ ((row & 7) << 4)));
            }
            #pragma unroll
            for (int m = 0; m < 4; ++m)
                #pragma unroll
                for (int n = 0; n < 4; ++n)
                    acc[m][n] = __builtin_amdgcn_mfma_f32_16x16x32_bf16(
                        av[m], bv[n], acc[m][n], 0, 0, 0);
        }
    }

    float lsum = 0.f;
    const int oc  = lane & 15;
    const int orr = (lane >> 4) * 4;

    int lj[4];
    #pragma unroll
    for (int n = 0; n < 4; ++n) lj[n] = labB[wc * 64 + n * 16 + oc];

    #pragma unroll
    for (int m = 0; m < 4; ++m) {
        #pragma unroll
        for (int j = 0; j < 4; ++j) {
            const int li = labA[wr * 64 + m * 16 + orr + j];
            #pragma unroll
            for (int n = 0; n < 4; ++n) {
                const float d = acc[m][n][j];
                const float s = (li == lj[n]) ? 1.f : -1.f;
                lsum += fmaxf(fmaf(s, d - BETHE_C, ALPHA_C), 0.f);
            }
        }
    }

    const float w = (ti == tj) ? 1.f : 2.f;
    lsum *= w * inv_n;

    #pragma unroll
    for (int off = 32; off > 0; off >>= 1)
        lsum += __shfl_down(lsum, off, 64);

    if (lane == 0) wsum[wid] = lsum;
    __syncthreads();
    if (t == 0) atomicAdd(out, wsum[0] + wsum[1] + wsum[2] + wsum[3]);
}

extern "C" void kernel_launch(void* const* d_in, const int* in_sizes, int n_in,
                              void* d_out, int out_size, void* d_ws, size_t ws_size,
                              hipStream_t stream) {
    const float* X      = (const float*)d_in[0];
    const int*   labels = (const int*)d_in[1];
    float*       out    = (float*)d_out;

    const int N = in_sizes[1];               // 8192

    const size_t xb_bytes = (size_t)N * 128 * sizeof(unsigned short);  // 2 MB
    const int NP   = N / 64;                 // 128 panels
    const int NCHY = (NP + CH - 1) / CH;     // 32
    const int npart = NP * NCHY;             // 4096
    const size_t need = xb_bytes + (size_t)npart * sizeof(float);

    if ((N % 64) == 0 && ws_size >= need) {
        unsigned short* Xb       = (unsigned short*)d_ws;
        float*          partials = (float*)((char*)d_ws + xb_bytes);
        const int cblocks = (N * 16 + 255) / 256;
        convert_kernel<<<cblocks, 256, 0, stream>>>(X, Xb, N);
        margin_reg<<<dim3(NP, NCHY), 64, 0, stream>>>(Xb, labels, partials, NP);
        reduce_kernel<<<1, 256, 0, stream>>>(partials, out, npart, 1.0f / (float)N);
    } else {
        const int NT = N / 128;
        const int nblocks = NT * (NT + 1) / 2;
        zero_kernel<<<1, 1, 0, stream>>>(out);
        margin_tile_kernel<<<nblocks, 256, 0, stream>>>(X, labels, out, NT, 1.0f / (float)N);
    }
}